// Round 2
// baseline (418.215 us; speedup 1.0000x reference)
//
#include <hip/hip_runtime.h>

typedef unsigned short u16;
typedef unsigned int u32;
typedef __attribute__((ext_vector_type(8))) short short8;
typedef __attribute__((ext_vector_type(4))) float f32x4;

__device__ __forceinline__ u16 f2bf(float f) {
  u32 u = __float_as_uint(f);
  u += 0x7FFFu + ((u >> 16) & 1u);
  return (u16)(u >> 16);
}

// packed f32x2 -> bf16x2 (RNE), gfx950 HW op; no builtin exists (T12 recipe)
__device__ __forceinline__ u32 cvt_pk_bf16(float lo, float hi) {
  u32 r;
  asm("v_cvt_pk_bf16_f32 %0, %1, %2" : "=v"(r) : "v"(lo), "v"(hi));
  return r;
}

// exact-erf GELU via A&S 7.1.26 (|err| ~1.5e-7), branch-free, ~16 VALU ops.
// Coefficients pre-halved so h = 0.5*erfc(|x/sqrt2|) directly.
__device__ __forceinline__ float fast_gelu(float x) {
  float xs = 0.70710678118654752f * x;
  float ax = __builtin_fabsf(xs);
  float t  = __builtin_amdgcn_rcpf(__builtin_fmaf(0.3275911f, ax, 1.0f));
  float p  = __builtin_fmaf(__builtin_fmaf(__builtin_fmaf(__builtin_fmaf(
               0.5307027145f, t, -0.7265760135f), t, 0.7107068705f), t,
               -0.142248368f), t, 0.127414796f);
  float e  = __expf(-(ax * ax));
  float h  = (p * t) * e;                    // 0.5*erfc(|xs|), ->0 for large |x|
  float phi = (x >= 0.0f) ? (1.0f - h) : h;  // branch-free cndmask
  return x * phi;
}

// swizzled byte offset inside a [rows][128 bf16] (256B-stride) LDS tile
__device__ __forceinline__ int swz(int row, int inrow_byte) {
  return (row * 256 + inrow_byte) ^ ((row & 7) << 4);
}

// ---- prep: weights -> bf16 transposed [n][k] in ws ----
// ws (u16): [0,65536): layers 1..4: layer*16384 + n*128 + k  (W1 k-padded 48->128)
//           [65536,67584): W5T: n*128 + k  (16 cols, 4 real)
__global__ void prep_weights(const float* __restrict__ W1, const float* __restrict__ W2,
                             const float* __restrict__ W3, const float* __restrict__ W4,
                             const float* __restrict__ W5, u16* __restrict__ ws) {
  int idx = blockIdx.x * 256 + threadIdx.x;
  if (idx < 65536) {
    int layer = idx >> 14, rem = idx & 16383;
    int n = rem >> 7, k = rem & 127;
    float v;
    if (layer == 0)      v = (k < 48) ? W1[k * 128 + n] : 0.f;
    else if (layer == 1) v = W2[k * 128 + n];
    else if (layer == 2) v = W3[k * 128 + n];
    else                 v = W4[k * 128 + n];
    ws[idx] = f2bf(v);
  } else if (idx < 67584) {
    int i2 = idx - 65536;
    int n = i2 >> 7, k = i2 & 127;
    ws[idx] = f2bf((n < 4) ? W5[k * 4 + n] : 0.f);
  }
}

__global__ __launch_bounds__(256) void domino_main(
    const float* __restrict__ qp, const float* __restrict__ pts,
    const float* __restrict__ freqs,
    const float* __restrict__ b1, const float* __restrict__ b2,
    const float* __restrict__ b3, const float* __restrict__ b4,
    const float* __restrict__ b5, const int* __restrict__ mapping,
    const u16* __restrict__ wsW, float* __restrict__ out) {
  __shared__ alignas(16) u16 Abuf[64 * 128];    // 16KB activations (bf16, swizzled)
  __shared__ alignas(16) u16 Wbuf[128 * 128];   // 32KB current-layer W^T (bf16, swizzled)
  char* const ab = (char*)Abuf;
  char* const wb = (char*)Wbuf;

  const int tid  = threadIdx.x;
  const int lane = tid & 63;
  const int wid  = tid >> 6;
  const int blk  = blockIdx.x;
  const int l15  = lane & 15;
  const int lk   = lane >> 4;

  const int RB0 = (wid & 1) * 32;     // wave's 32-row band
  const int CB0 = (wid >> 1) * 64;    // wave's 64-col band

  // ---- hoist all biases into registers (latency hidden under features) ----
  float bias[4][4];
  {
    const float* const BS[4] = {b1, b2, b3, b4};
    #pragma unroll
    for (int L = 0; L < 4; ++L)
      #pragma unroll
      for (int cb = 0; cb < 4; ++cb)
        bias[L][cb] = BS[L][CB0 + cb * 16 + l15];
  }

  // ---- zero A (pad region for k>=48) ----
  {
    f32x4 z = {0.f, 0.f, 0.f, 0.f};
    #pragma unroll
    for (int c = 0; c < 4; ++c)
      *(f32x4*)(ab + c * 4096 + tid * 16) = z;
  }
  __syncthreads();

  // ---- gather + fourier features: rows r = q*8 + neighbor ----
  {
    const int r = tid >> 2, p = tid & 3;
    const int mg = blk * 8 + (r >> 3);
    const int nb = mapping[blk * 64 + r];
    float rel[3];
    #pragma unroll
    for (int d = 0; d < 3; ++d) rel[d] = pts[nb * 3 + d] - qp[mg * 3 + d];
    #pragma unroll
    for (int f2 = 0; f2 < 2; ++f2) {
      const int f = p * 2 + f2;
      const float fr = freqs[f];
      #pragma unroll
      for (int d = 0; d < 3; ++d) {
        const float a = rel[d] * fr;
        const int j = f * 3 + d;                           // matches (..,F,D) reshape
        *(u16*)(ab + swz(r, j * 2))        = f2bf(__sinf(a));
        *(u16*)(ab + swz(r, (24 + j) * 2)) = f2bf(__cosf(a));
      }
    }
  }

  const int wsx = (tid * 16) ^ (((tid >> 4) & 7) << 4);  // W staging dst (swizzled)

  #pragma unroll
  for (int layer = 0; layer < 4; ++layer) {
    // stage W^T[layer] -> Wbuf (row n swizzle constant per thread across c)
    {
      const char* src = (const char*)(wsW + layer * 16384);
      #pragma unroll
      for (int c = 0; c < 8; ++c) {
        f32x4 v = *(const f32x4*)(src + c * 4096 + tid * 16);
        *(f32x4*)(wb + wsx + c * 4096) = v;
      }
    }
    __syncthreads();   // staging + (iter0) features + prev writeback visible

    f32x4 acc[2][4];
    #pragma unroll
    for (int cb = 0; cb < 4; ++cb) {
      const float bv = bias[layer][cb];
      f32x4 bb = {bv, bv, bv, bv};
      acc[0][cb] = bb;
      acc[1][cb] = bb;
    }
    const int KKn = (layer == 0) ? 2 : 4;   // layer0: K=48 (padded to 64)
    #pragma unroll
    for (int kk = 0; kk < 4; ++kk) {
      if (kk < KKn) {
        const short8 a0 = *(const short8*)(ab + swz(RB0 + l15,      kk * 64 + lk * 16));
        const short8 a1 = *(const short8*)(ab + swz(RB0 + 16 + l15, kk * 64 + lk * 16));
        #pragma unroll
        for (int cb = 0; cb < 4; ++cb) {
          const int n = CB0 + cb * 16 + l15;
          const short8 bfrag = *(const short8*)(wb + swz(n, kk * 64 + lk * 16));
          acc[0][cb] = __builtin_amdgcn_mfma_f32_16x16x32_bf16(a0, bfrag, acc[0][cb], 0, 0, 0);
          acc[1][cb] = __builtin_amdgcn_mfma_f32_16x16x32_bf16(a1, bfrag, acc[1][cb], 0, 0, 0);
        }
      }
    }
    __syncthreads();   // everyone done reading A & W before A is overwritten

    // GELU + packed bf16 writeback  (C/D map: col=lane&15, row=(lane>>4)*4+reg)
    #pragma unroll
    for (int rb = 0; rb < 2; ++rb) {
      #pragma unroll
      for (int rg = 0; rg < 4; ++rg) {
        const int row = RB0 + rb * 16 + lk * 4 + rg;
        const float g0 = fast_gelu(acc[rb][0][rg]);
        const float g1 = fast_gelu(acc[rb][1][rg]);
        const float g2 = fast_gelu(acc[rb][2][rg]);
        const float g3 = fast_gelu(acc[rb][3][rg]);
        const u32 w01 = cvt_pk_bf16(g0, g1);
        const u32 w23 = cvt_pk_bf16(g2, g3);
        const int cb0 = (CB0 + l15) * 2;
        *(u16*)(ab + swz(row, cb0))      = (u16)w01;
        *(u16*)(ab + swz(row, cb0 + 32)) = (u16)(w01 >> 16);
        *(u16*)(ab + swz(row, cb0 + 64)) = (u16)w23;
        *(u16*)(ab + swz(row, cb0 + 96)) = (u16)(w23 >> 16);
      }
    }
  }

  // ---- layer 5: [64x128] @ W5T[16x128], then mean over 8 neighbors ----
  {
    const char* src = (const char*)(wsW + 65536);
    const int off = tid * 16;            // 4KB total
    const int n = off >> 8;
    f32x4 v = *(const f32x4*)(src + off);
    *(f32x4*)(wb + (off ^ ((n & 7) << 4))) = v;
  }
  __syncthreads();   // also makes layer-4 writeback visible

  f32x4 acc5 = {0.f, 0.f, 0.f, 0.f};
  #pragma unroll
  for (int kk = 0; kk < 4; ++kk) {
    const int row = wid * 16 + l15;      // each wave: its own 16 rows x 16 cols
    const short8 a = *(const short8*)(ab + swz(row, kk * 64 + lk * 16));
    const short8 b = *(const short8*)(wb + swz(l15, kk * 64 + lk * 16));
    acc5 = __builtin_amdgcn_mfma_f32_16x16x32_bf16(a, b, acc5, 0, 0, 0);
  }
  // lane holds rows (lk*4 + 0..3) of its 16-row tile at col l15:
  // sum 4 in-lane rows, then xor-16 pairs rows {0-7}|{8-15} -> per-query sums
  float s4 = acc5[0] + acc5[1] + acc5[2] + acc5[3];
  s4 += __shfl_xor(s4, 16, 64);
  if (((lane >> 4) & 1) == 0 && l15 < 4) {
    const int q = wid * 2 + (lane >> 5);
    out[(blk * 8 + q) * 4 + l15] = 0.125f * s4 + b5[l15];
  }
}

extern "C" void kernel_launch(void* const* d_in, const int* in_sizes, int n_in,
                              void* d_out, int out_size, void* d_ws, size_t ws_size,
                              hipStream_t stream) {
  const float* qp      = (const float*)d_in[0];
  const float* pts     = (const float*)d_in[1];
  const float* freqs   = (const float*)d_in[2];
  const float* W1      = (const float*)d_in[3];
  const float* b1      = (const float*)d_in[4];
  const float* W2      = (const float*)d_in[5];
  const float* b2      = (const float*)d_in[6];
  const float* W3      = (const float*)d_in[7];
  const float* b3      = (const float*)d_in[8];
  const float* W4      = (const float*)d_in[9];
  const float* b4      = (const float*)d_in[10];
  const float* W5      = (const float*)d_in[11];
  const float* b5      = (const float*)d_in[12];
  const int*   mapping = (const int*)d_in[13];
  u16* ws = (u16*)d_ws;
  float* out = (float*)d_out;

  prep_weights<<<dim3(264), dim3(256), 0, stream>>>(W1, W2, W3, W4, W5, ws);
  domino_main<<<dim3(16384), dim3(256), 0, stream>>>(
      qp, pts, freqs, b1, b2, b3, b4, b5, mapping, ws, out);
}

// Round 3
// 385.620 us; speedup vs baseline: 1.0845x; 1.0845x over previous
//
#include <hip/hip_runtime.h>

typedef unsigned short u16;
typedef unsigned int u32;
typedef __attribute__((ext_vector_type(8))) short short8;
typedef __attribute__((ext_vector_type(4))) float f32x4;

__device__ __forceinline__ u16 f2bf(float f) {
  u32 u = __float_as_uint(f);
  u += 0x7FFFu + ((u >> 16) & 1u);
  return (u16)(u >> 16);
}

// Pure-polynomial exact-GELU for |x| <= 1.5 (error < 3e-6 there).
// Phi(x) = 0.5 + x*P(x^2), P = Taylor of erf(x/sqrt2)/(2x); 8 terms.
__device__ __forceinline__ float gelu_poly(float x) {
  const float v = x * x;
  float p = __builtin_fmaf(-4.12267e-8f, v, 6.65969e-7f);
  p = __builtin_fmaf(p, v, -9.44466e-6f);
  p = __builtin_fmaf(p, v, 1.15437e-4f);
  p = __builtin_fmaf(p, v, -1.1873282e-3f);
  p = __builtin_fmaf(p, v, 9.973557e-3f);
  p = __builtin_fmaf(p, v, -6.649038e-2f);
  p = __builtin_fmaf(p, v, 0.3989422804f);
  return x * __builtin_fmaf(x, p, 0.5f);
}

// Fallback for rare |x| > 1.5: A&S 7.1.26 erfc (|err|~1.5e-7), branch-free.
__device__ __forceinline__ float gelu_as(float x) {
  float ax = __builtin_fabsf(0.70710678118654752f * x);
  float t  = __builtin_amdgcn_rcpf(__builtin_fmaf(0.3275911f, ax, 1.0f));
  float p  = __builtin_fmaf(__builtin_fmaf(__builtin_fmaf(__builtin_fmaf(
               0.5307027145f, t, -0.7265760135f), t, 0.7107068705f), t,
               -0.142248368f), t, 0.127414796f);
  float e  = __expf(-(ax * ax));
  float h  = (p * t) * e;
  float phi = (x >= 0.0f) ? (1.0f - h) : h;
  return x * phi;
}

// swizzled byte offset inside a [rows][128 bf16] (256B-stride) LDS tile
__device__ __forceinline__ int swz(int row, int inrow_byte) {
  return (row * 256 + inrow_byte) ^ ((row & 7) << 4);
}

// ---- prep: weights -> bf16 transposed [n][k] in ws ----
__global__ void prep_weights(const float* __restrict__ W1, const float* __restrict__ W2,
                             const float* __restrict__ W3, const float* __restrict__ W4,
                             const float* __restrict__ W5, u16* __restrict__ ws) {
  int idx = blockIdx.x * 256 + threadIdx.x;
  if (idx < 65536) {
    int layer = idx >> 14, rem = idx & 16383;
    int n = rem >> 7, k = rem & 127;
    float v;
    if (layer == 0)      v = (k < 48) ? W1[k * 128 + n] : 0.f;
    else if (layer == 1) v = W2[k * 128 + n];
    else if (layer == 2) v = W3[k * 128 + n];
    else                 v = W4[k * 128 + n];
    ws[idx] = f2bf(v);
  } else if (idx < 67584) {
    int i2 = idx - 65536;
    int n = i2 >> 7, k = i2 & 127;
    ws[idx] = f2bf((n < 4) ? W5[k * 4 + n] : 0.f);
  }
}

__global__ __launch_bounds__(256) void domino_main(
    const float* __restrict__ qp, const float* __restrict__ pts,
    const float* __restrict__ freqs,
    const float* __restrict__ b1, const float* __restrict__ b2,
    const float* __restrict__ b3, const float* __restrict__ b4,
    const float* __restrict__ b5, const int* __restrict__ mapping,
    const u16* __restrict__ wsW, float* __restrict__ out) {
  __shared__ alignas(16) u16 Abuf[64 * 128];    // 16KB activations (bf16, swizzled)
  __shared__ alignas(16) u16 Wbuf[128 * 128];   // 32KB current-layer W^T (bf16, swizzled)
  char* const ab = (char*)Abuf;
  char* const wb = (char*)Wbuf;

  const int tid  = threadIdx.x;
  const int lane = tid & 63;
  const int wid  = tid >> 6;
  const int blk  = blockIdx.x;
  const int l15  = lane & 15;
  const int lk   = lane >> 4;

  const int RB0 = (wid & 1) * 32;     // wave's 32-row band
  const int CB0 = (wid >> 1) * 64;    // wave's 64-col band

  // ---- hoist all biases into registers ----
  float bias[4][4];
  {
    const float* const BS[4] = {b1, b2, b3, b4};
    #pragma unroll
    for (int L = 0; L < 4; ++L)
      #pragma unroll
      for (int cb = 0; cb < 4; ++cb)
        bias[L][cb] = BS[L][CB0 + cb * 16 + l15];
  }

  // ---- zero A (pad region for k>=48) ----
  {
    f32x4 z = {0.f, 0.f, 0.f, 0.f};
    #pragma unroll
    for (int c = 0; c < 4; ++c)
      *(f32x4*)(ab + c * 4096 + tid * 16) = z;
  }
  __syncthreads();

  // ---- gather + fourier features: rows r = q*8 + neighbor ----
  {
    const int r = tid >> 2, p = tid & 3;
    const int mg = blk * 8 + (r >> 3);
    const int nb = mapping[blk * 64 + r];
    float rel[3];
    #pragma unroll
    for (int d = 0; d < 3; ++d) rel[d] = pts[nb * 3 + d] - qp[mg * 3 + d];
    #pragma unroll
    for (int f2 = 0; f2 < 2; ++f2) {
      const int f = p * 2 + f2;
      const float fr = freqs[f];
      #pragma unroll
      for (int d = 0; d < 3; ++d) {
        const float a = rel[d] * fr;
        const int j = f * 3 + d;                           // matches (..,F,D) reshape
        *(u16*)(ab + swz(r, j * 2))        = f2bf(__sinf(a));
        *(u16*)(ab + swz(r, (24 + j) * 2)) = f2bf(__cosf(a));
      }
    }
  }

  const int wsx = (tid * 16) ^ (((tid >> 4) & 7) << 4);  // W staging dst (swizzled)

  #pragma unroll
  for (int layer = 0; layer < 4; ++layer) {
    // stage W^T[layer] -> Wbuf (row n swizzle constant per thread across c)
    {
      const char* src = (const char*)(wsW + layer * 16384);
      #pragma unroll
      for (int c = 0; c < 8; ++c) {
        f32x4 v = *(const f32x4*)(src + c * 4096 + tid * 16);
        *(f32x4*)(wb + wsx + c * 4096) = v;
      }
    }
    __syncthreads();   // staging + (iter0) features + prev writeback visible

    f32x4 acc[2][4];
    #pragma unroll
    for (int cb = 0; cb < 4; ++cb) {
      const float bv = bias[layer][cb];
      f32x4 bb = {bv, bv, bv, bv};
      acc[0][cb] = bb;
      acc[1][cb] = bb;
    }
    const int KKn = (layer == 0) ? 2 : 4;   // layer0: K=48 (padded to 64)
    #pragma unroll
    for (int kk = 0; kk < 4; ++kk) {
      if (kk < KKn) {
        const short8 a0 = *(const short8*)(ab + swz(RB0 + l15,      kk * 64 + lk * 16));
        const short8 a1 = *(const short8*)(ab + swz(RB0 + 16 + l15, kk * 64 + lk * 16));
        #pragma unroll
        for (int cb = 0; cb < 4; ++cb) {
          const int n = CB0 + cb * 16 + l15;
          const short8 bfrag = *(const short8*)(wb + swz(n, kk * 64 + lk * 16));
          acc[0][cb] = __builtin_amdgcn_mfma_f32_16x16x32_bf16(a0, bfrag, acc[0][cb], 0, 0, 0);
          acc[1][cb] = __builtin_amdgcn_mfma_f32_16x16x32_bf16(a1, bfrag, acc[1][cb], 0, 0, 0);
        }
      }
    }
    __syncthreads();   // everyone done reading A & W before A is overwritten

    // GELU + bf16 writeback  (C/D map: col=lane&15, row=(lane>>4)*4+reg)
    #pragma unroll
    for (int rb = 0; rb < 2; ++rb) {
      #pragma unroll
      for (int rg = 0; rg < 4; ++rg) {
        const int row = RB0 + rb * 16 + lk * 4 + rg;
        const float x0 = acc[rb][0][rg], x1 = acc[rb][1][rg];
        const float x2 = acc[rb][2][rg], x3 = acc[rb][3][rg];
        const float m = __builtin_fmaxf(
            __builtin_fmaxf(__builtin_fabsf(x0), __builtin_fabsf(x1)),
            __builtin_fmaxf(__builtin_fabsf(x2), __builtin_fabsf(x3)));
        float g0, g1, g2, g3;
        if (__any(m > 1.5f)) {           // rare wave-uniform fallback
          g0 = gelu_as(x0); g1 = gelu_as(x1); g2 = gelu_as(x2); g3 = gelu_as(x3);
        } else {
          g0 = gelu_poly(x0); g1 = gelu_poly(x1); g2 = gelu_poly(x2); g3 = gelu_poly(x3);
        }
        const int cb0 = (CB0 + l15) * 2;
        *(u16*)(ab + swz(row, cb0))      = f2bf(g0);
        *(u16*)(ab + swz(row, cb0 + 32)) = f2bf(g1);
        *(u16*)(ab + swz(row, cb0 + 64)) = f2bf(g2);
        *(u16*)(ab + swz(row, cb0 + 96)) = f2bf(g3);
      }
    }
  }

  // ---- layer 5: [64x128] @ W5T[16x128], then mean over 8 neighbors ----
  {
    const char* src = (const char*)(wsW + 65536);
    const int off = tid * 16;            // 4KB total
    const int n = off >> 8;
    f32x4 v = *(const f32x4*)(src + off);
    *(f32x4*)(wb + (off ^ ((n & 7) << 4))) = v;
  }
  __syncthreads();   // also makes layer-4 writeback visible

  f32x4 acc5 = {0.f, 0.f, 0.f, 0.f};
  #pragma unroll
  for (int kk = 0; kk < 4; ++kk) {
    const int row = wid * 16 + l15;      // each wave: its own 16 rows x 16 cols
    const short8 a = *(const short8*)(ab + swz(row, kk * 64 + lk * 16));
    const short8 b = *(const short8*)(wb + swz(l15, kk * 64 + lk * 16));
    acc5 = __builtin_amdgcn_mfma_f32_16x16x32_bf16(a, b, acc5, 0, 0, 0);
  }
  // lane holds rows (lk*4 + 0..3) of its 16-row tile at col l15:
  // sum 4 in-lane rows, then xor-16 pairs rows {0-7}|{8-15} -> per-query sums
  float s4 = acc5[0] + acc5[1] + acc5[2] + acc5[3];
  s4 += __shfl_xor(s4, 16, 64);
  if (((lane >> 4) & 1) == 0 && l15 < 4) {
    const int q = wid * 2 + (lane >> 5);
    out[(blk * 8 + q) * 4 + l15] = 0.125f * s4 + b5[l15];
  }
}

extern "C" void kernel_launch(void* const* d_in, const int* in_sizes, int n_in,
                              void* d_out, int out_size, void* d_ws, size_t ws_size,
                              hipStream_t stream) {
  const float* qp      = (const float*)d_in[0];
  const float* pts     = (const float*)d_in[1];
  const float* freqs   = (const float*)d_in[2];
  const float* W1      = (const float*)d_in[3];
  const float* b1      = (const float*)d_in[4];
  const float* W2      = (const float*)d_in[5];
  const float* b2      = (const float*)d_in[6];
  const float* W3      = (const float*)d_in[7];
  const float* b3      = (const float*)d_in[8];
  const float* W4      = (const float*)d_in[9];
  const float* b4      = (const float*)d_in[10];
  const float* W5      = (const float*)d_in[11];
  const float* b5      = (const float*)d_in[12];
  const int*   mapping = (const int*)d_in[13];
  u16* ws = (u16*)d_ws;
  float* out = (float*)d_out;

  prep_weights<<<dim3(264), dim3(256), 0, stream>>>(W1, W2, W3, W4, W5, ws);
  domino_main<<<dim3(16384), dim3(256), 0, stream>>>(
      qp, pts, freqs, b1, b2, b3, b4, b5, mapping, ws, out);
}

// Round 4
// 379.328 us; speedup vs baseline: 1.1025x; 1.0166x over previous
//
#include <hip/hip_runtime.h>

typedef unsigned short u16;
typedef unsigned int u32;
typedef __attribute__((ext_vector_type(8))) short short8;
typedef __attribute__((ext_vector_type(4))) float f32x4;

#define AS1 __attribute__((address_space(1)))
#define AS3 __attribute__((address_space(3)))

__device__ __forceinline__ u16 f2bf(float f) {
  u32 u = __float_as_uint(f);
  u += 0x7FFFu + ((u >> 16) & 1u);
  return (u16)(u >> 16);
}

// Pure-polynomial exact-GELU for |x| <= 1.5 (error < 3e-6 there).
__device__ __forceinline__ float gelu_poly(float x) {
  const float v = x * x;
  float p = __builtin_fmaf(-4.12267e-8f, v, 6.65969e-7f);
  p = __builtin_fmaf(p, v, -9.44466e-6f);
  p = __builtin_fmaf(p, v, 1.15437e-4f);
  p = __builtin_fmaf(p, v, -1.1873282e-3f);
  p = __builtin_fmaf(p, v, 9.973557e-3f);
  p = __builtin_fmaf(p, v, -6.649038e-2f);
  p = __builtin_fmaf(p, v, 0.3989422804f);
  return x * __builtin_fmaf(x, p, 0.5f);
}

// Fallback for rare |x| > 1.5: A&S 7.1.26 erfc (|err|~1.5e-7), branch-free.
__device__ __forceinline__ float gelu_as(float x) {
  float ax = __builtin_fabsf(0.70710678118654752f * x);
  float t  = __builtin_amdgcn_rcpf(__builtin_fmaf(0.3275911f, ax, 1.0f));
  float p  = __builtin_fmaf(__builtin_fmaf(__builtin_fmaf(__builtin_fmaf(
               0.5307027145f, t, -0.7265760135f), t, 0.7107068705f), t,
               -0.142248368f), t, 0.127414796f);
  float e  = __expf(-(ax * ax));
  float h  = (p * t) * e;
  float phi = (x >= 0.0f) ? (1.0f - h) : h;
  return x * phi;
}

// swizzled byte offset inside a [rows][128 bf16] (256B-stride) LDS tile
__device__ __forceinline__ int swz(int row, int inrow_byte) {
  return (row * 256 + inrow_byte) ^ ((row & 7) << 4);
}

// ---- prep: weights -> bf16 transposed [n][k], PRE-SWIZZLED for linear
// global_load_lds DMA (LDS dest written linearly; ds_reads apply the XOR).
// u16 index i within a 16384-elem layer: n = i>>7, k = (i&127) ^ ((n&7)<<3).
// ws (u16): [0,65536): layers 1..4 ; [65536,67584): W5T (16 cols, 4 real)
__global__ void prep_weights(const float* __restrict__ W1, const float* __restrict__ W2,
                             const float* __restrict__ W3, const float* __restrict__ W4,
                             const float* __restrict__ W5, u16* __restrict__ ws) {
  int idx = blockIdx.x * 256 + threadIdx.x;
  if (idx < 65536) {
    int L = idx >> 14, i = idx & 16383;
    int n = i >> 7;
    int k = (i & 127) ^ ((n & 7) << 3);
    float v;
    if (L == 0)      v = (k < 48) ? W1[k * 128 + n] : 0.f;
    else if (L == 1) v = W2[k * 128 + n];
    else if (L == 2) v = W3[k * 128 + n];
    else             v = W4[k * 128 + n];
    ws[idx] = f2bf(v);
  } else if (idx < 67584) {
    int i = idx - 65536;
    int n = i >> 7;
    int k = (i & 127) ^ ((n & 7) << 3);
    ws[idx] = f2bf((n < 4) ? W5[k * 4 + n] : 0.f);
  }
}

__global__ __launch_bounds__(512) void domino_main(
    const float* __restrict__ qp, const float* __restrict__ pts,
    const float* __restrict__ freqs,
    const float* __restrict__ b1, const float* __restrict__ b2,
    const float* __restrict__ b3, const float* __restrict__ b4,
    const float* __restrict__ b5, const int* __restrict__ mapping,
    const u16* __restrict__ wsW, float* __restrict__ out) {
  __shared__ alignas(16) u16 Abuf[128 * 128];   // 32KB activations (bf16, swizzled)
  __shared__ alignas(16) u16 Wbuf[128 * 128];   // 32KB current-layer W^T (DMA-filled)
  char* const ab = (char*)Abuf;
  char* const wb = (char*)Wbuf;

  const int tid  = threadIdx.x;
  const int lane = tid & 63;
  const int wid  = tid >> 6;
  const int blk  = blockIdx.x;
  const int l15  = lane & 15;
  const int lk   = lane >> 4;

  const int RB0 = (wid & 3) * 32;     // wave's 32-row band (of 128)
  const int CB0 = (wid >> 2) * 64;    // wave's 64-col band

  // ---- issue W1 DMA immediately (latency hides under feature gen) ----
  {
    const char* src = (const char*)wsW;
    #pragma unroll
    for (int c = 0; c < 4; ++c)
      __builtin_amdgcn_global_load_lds(
          (const AS1 void*)(const void*)(src + c * 8192 + tid * 16),
          (AS3 void*)(void*)(wb + c * 8192 + wid * 1024), 16, 0, 0);
  }

  // ---- hoist all biases into registers ----
  float bias[4][4];
  {
    const float* const BS[4] = {b1, b2, b3, b4};
    #pragma unroll
    for (int L = 0; L < 4; ++L)
      #pragma unroll
      for (int cb = 0; cb < 4; ++cb)
        bias[L][cb] = BS[L][CB0 + cb * 16 + l15];
  }

  // ---- zero A (pad region for k>=48) ----
  {
    f32x4 z = {0.f, 0.f, 0.f, 0.f};
    #pragma unroll
    for (int c = 0; c < 4; ++c)
      *(f32x4*)(ab + c * 8192 + tid * 16) = z;
  }
  __syncthreads();   // A zeroed before feature scatter (avoid write races on pads)

  // ---- gather + fourier features: rows r = q*8 + neighbor (128 rows) ----
  {
    const int r = tid >> 2, p = tid & 3;
    const int mg = blk * 16 + (r >> 3);
    const int nb = mapping[blk * 128 + r];
    float rel[3];
    #pragma unroll
    for (int d = 0; d < 3; ++d) rel[d] = pts[nb * 3 + d] - qp[mg * 3 + d];
    #pragma unroll
    for (int f2 = 0; f2 < 2; ++f2) {
      const int f = p * 2 + f2;
      const float fr = freqs[f];
      #pragma unroll
      for (int d = 0; d < 3; ++d) {
        const float a = rel[d] * fr;
        const int j = f * 3 + d;                           // matches (..,F,D) reshape
        *(u16*)(ab + swz(r, j * 2))        = f2bf(__sinf(a));
        *(u16*)(ab + swz(r, (24 + j) * 2)) = f2bf(__cosf(a));
      }
    }
  }

  #pragma unroll
  for (int layer = 0; layer < 4; ++layer) {
    // barrier_pre: drains W DMA (vmcnt0 before s_barrier) + A writes visible
    __syncthreads();

    f32x4 acc[2][4];
    #pragma unroll
    for (int cb = 0; cb < 4; ++cb) {
      const float bv = bias[layer][cb];
      f32x4 bb = {bv, bv, bv, bv};
      acc[0][cb] = bb;
      acc[1][cb] = bb;
    }
    const int KKn = (layer == 0) ? 2 : 4;   // layer0: K=48 (padded to 64)
    #pragma unroll
    for (int kk = 0; kk < 4; ++kk) {
      if (kk < KKn) {
        const short8 a0 = *(const short8*)(ab + swz(RB0 + l15,      kk * 64 + lk * 16));
        const short8 a1 = *(const short8*)(ab + swz(RB0 + 16 + l15, kk * 64 + lk * 16));
        #pragma unroll
        for (int cb = 0; cb < 4; ++cb) {
          const int n = CB0 + cb * 16 + l15;
          const short8 bfrag = *(const short8*)(wb + swz(n, kk * 64 + lk * 16));
          acc[0][cb] = __builtin_amdgcn_mfma_f32_16x16x32_bf16(a0, bfrag, acc[0][cb], 0, 0, 0);
          acc[1][cb] = __builtin_amdgcn_mfma_f32_16x16x32_bf16(a1, bfrag, acc[1][cb], 0, 0, 0);
        }
      }
    }
    __syncthreads();   // all waves done reading A and W[layer]

    // issue next W DMA now; L2 latency hides under the GELU epilogue below,
    // and the compiler's vmcnt(0) drain sits at the next barrier_pre.
    if (layer < 3) {
      const char* src = (const char*)(wsW + (layer + 1) * 16384);
      #pragma unroll
      for (int c = 0; c < 4; ++c)
        __builtin_amdgcn_global_load_lds(
            (const AS1 void*)(const void*)(src + c * 8192 + tid * 16),
            (AS3 void*)(void*)(wb + c * 8192 + wid * 1024), 16, 0, 0);
    } else {
      if (tid < 256)   // 4KB W5 tile, waves 0-3 (wave-uniform predicate)
        __builtin_amdgcn_global_load_lds(
            (const AS1 void*)(const void*)((const char*)(wsW + 65536) + tid * 16),
            (AS3 void*)(void*)(wb + wid * 1024), 16, 0, 0);
    }

    // GELU + bf16 writeback  (C/D map: col=lane&15, row=(lane>>4)*4+reg)
    #pragma unroll
    for (int rb = 0; rb < 2; ++rb) {
      #pragma unroll
      for (int rg = 0; rg < 4; ++rg) {
        const int row = RB0 + rb * 16 + lk * 4 + rg;
        const float x0 = acc[rb][0][rg], x1 = acc[rb][1][rg];
        const float x2 = acc[rb][2][rg], x3 = acc[rb][3][rg];
        const float m = __builtin_fmaxf(
            __builtin_fmaxf(__builtin_fabsf(x0), __builtin_fabsf(x1)),
            __builtin_fmaxf(__builtin_fabsf(x2), __builtin_fabsf(x3)));
        float g0, g1, g2, g3;
        if (__any(m > 1.5f)) {           // rare wave-uniform fallback
          g0 = gelu_as(x0); g1 = gelu_as(x1); g2 = gelu_as(x2); g3 = gelu_as(x3);
        } else {
          g0 = gelu_poly(x0); g1 = gelu_poly(x1); g2 = gelu_poly(x2); g3 = gelu_poly(x3);
        }
        const int cb0 = (CB0 + l15) * 2;
        *(u16*)(ab + swz(row, cb0))      = f2bf(g0);
        *(u16*)(ab + swz(row, cb0 + 32)) = f2bf(g1);
        *(u16*)(ab + swz(row, cb0 + 64)) = f2bf(g2);
        *(u16*)(ab + swz(row, cb0 + 96)) = f2bf(g3);
      }
    }
  }

  __syncthreads();   // W5 DMA drained + layer-4 writeback visible

  // ---- layer 5: [128x128] @ W5T[16x128], then mean over 8 neighbors ----
  f32x4 acc5 = {0.f, 0.f, 0.f, 0.f};
  #pragma unroll
  for (int kk = 0; kk < 4; ++kk) {
    const int row = wid * 16 + l15;      // each wave: its own 16 rows x 16 cols
    const short8 a = *(const short8*)(ab + swz(row, kk * 64 + lk * 16));
    const short8 b = *(const short8*)(wb + swz(l15, kk * 64 + lk * 16));
    acc5 = __builtin_amdgcn_mfma_f32_16x16x32_bf16(a, b, acc5, 0, 0, 0);
  }
  // D: col=l15=out-feature, row=lk*4+r=sample. Sum 4 in-lane samples, then
  // xor-16 joins lk pairs {0,1} / {2,3} -> per-query (8-neighbor) sums.
  float s4 = acc5[0] + acc5[1] + acc5[2] + acc5[3];
  s4 += __shfl_xor(s4, 16, 64);
  if (((lane >> 4) & 1) == 0 && l15 < 4) {
    const int q = wid * 2 + (lane >> 5);
    out[(blk * 16 + q) * 4 + l15] = 0.125f * s4 + b5[l15];
  }
}

extern "C" void kernel_launch(void* const* d_in, const int* in_sizes, int n_in,
                              void* d_out, int out_size, void* d_ws, size_t ws_size,
                              hipStream_t stream) {
  const float* qp      = (const float*)d_in[0];
  const float* pts     = (const float*)d_in[1];
  const float* freqs   = (const float*)d_in[2];
  const float* W1      = (const float*)d_in[3];
  const float* b1      = (const float*)d_in[4];
  const float* W2      = (const float*)d_in[5];
  const float* b2      = (const float*)d_in[6];
  const float* W3      = (const float*)d_in[7];
  const float* b3      = (const float*)d_in[8];
  const float* W4      = (const float*)d_in[9];
  const float* b4      = (const float*)d_in[10];
  const float* W5      = (const float*)d_in[11];
  const float* b5      = (const float*)d_in[12];
  const int*   mapping = (const int*)d_in[13];
  u16* ws = (u16*)d_ws;
  float* out = (float*)d_out;

  prep_weights<<<dim3(264), dim3(256), 0, stream>>>(W1, W2, W3, W4, W5, ws);
  // 131072 queries / 16 per block = 8192 blocks, 512 threads (8 waves)
  domino_main<<<dim3(8192), dim3(512), 0, stream>>>(
      qp, pts, freqs, b1, b2, b3, b4, b5, mapping, ws, out);
}